// Round 1
// baseline (318.944 us; speedup 1.0000x reference)
//
#include <hip/hip_runtime.h>

// Shapes (fixed by the reference):
//   lfi:    [B=4, U=9, H=256, W=256, V=9]  f32
//   f_maps: [B=4, H=256, W=256, N=64]      f32
//   out:    [B=4, U=9, Y=256, X=256, N=64] f32
#define BB 4
#define UU 9
#define HH 256
#define WW 256
#define VV 9
#define NF 64

// ---------------- Kernel 1: hv[b][w][n] = (1/H) * sum_h f_maps[b][h][w][n]
__global__ __launch_bounds__(256) void k_hv(const float* __restrict__ f,
                                            float* __restrict__ hv) {
    const int blk = blockIdx.x;            // b*W + w
    const int b = blk >> 8, w = blk & 255;
    const int t = threadIdx.x;
    const int n = t & 63, hc = t >> 6;     // 4 chunks of 64 h each

    float acc = 0.f;
    const float* p = f + (((size_t)(b * HH + hc * 64) * WW) + w) * NF + n;
    const size_t stride = (size_t)WW * NF; // one h step
    #pragma unroll 8
    for (int i = 0; i < 64; ++i) acc += p[(size_t)i * stride];

    __shared__ float red[4][64];
    red[hc][n] = acc;
    __syncthreads();
    if (t < 64) {
        float s = red[0][t] + red[1][t] + red[2][t] + red[3][t];
        hv[((size_t)b * WW + w) * NF + t] = s * (1.0f / HH);
    }
}

// ---------------- Kernel 2: per b:
//   s_mask[n] = H * sum_w hv[b][w][n]
//   hvmax[n]  = max_w hv[b][w][n]
//   comb[b][y][n] = s_mask[n] * hv[b][y][n] / hvmax[n]
__global__ __launch_bounds__(256) void k_comb(const float* __restrict__ hv,
                                              float* __restrict__ comb) {
    const int b = blockIdx.x;
    const int t = threadIdx.x;
    const int n = t & 63, c = t >> 6;      // 4 chunks of 64 w each

    float s = 0.f, m = -1e30f;
    const float* p = hv + ((size_t)b * WW + c * 64) * NF + n;
    #pragma unroll 8
    for (int i = 0; i < 64; ++i) {
        float v = p[(size_t)i * NF];
        s += v;
        m = fmaxf(m, v);
    }

    __shared__ float rs[4][64], rm[4][64];
    __shared__ float fscale[64];
    rs[c][n] = s;
    rm[c][n] = m;
    __syncthreads();
    if (t < 64) {
        float ssum = (rs[0][t] + rs[1][t] + rs[2][t] + rs[3][t]) * (float)HH;
        float smax = fmaxf(fmaxf(rm[0][t], rm[1][t]), fmaxf(rm[2][t], rm[3][t]));
        fscale[t] = ssum / smax;
    }
    __syncthreads();

    const float sc = fscale[n];
    const float* p2 = hv + ((size_t)b * WW + c * 64) * NF + n;
    float* q = comb + ((size_t)b * WW + c * 64) * NF + n;
    #pragma unroll 8
    for (int i = 0; i < 64; ++i) q[(size_t)i * NF] = p2[(size_t)i * NF] * sc;
}

// ---------------- Kernel 3: one wave per (b,u,y) row.
// out[pix*64 + n] = mean_v(lfi[pix*9 + v]) * comb[(b*256+y)*64 + n]
__global__ __launch_bounds__(256) void k_main(const float* __restrict__ lfi,
                                              const float* __restrict__ comb,
                                              float* __restrict__ out) {
    const int wid  = (int)((blockIdx.x * 256 + threadIdx.x) >> 6); // row id 0..9215
    const int lane = threadIdx.x & 63;
    const int y  = wid & 255;
    const int bu = wid >> 8;       // b*9+u
    const int b  = bu / 9;

    const int q   = lane & 15;     // n-quad
    const int sub = lane >> 4;     // sub-pixel within group of 4

    const size_t rowpix = (size_t)wid * 256;   // pixel index at x=0
    const float4 c4 = *(const float4*)(comb + ((size_t)(b * 256 + y)) * NF + q * 4);
    const float inv9 = 1.0f / 9.0f;

    #pragma unroll 2
    for (int g = 0; g < 64; ++g) {
        const size_t pix = rowpix + (size_t)g * 4 + sub;
        const float* lp = lfi + pix * 9;
        float s = lp[0] + lp[1] + lp[2] + lp[3] + lp[4]
                + lp[5] + lp[6] + lp[7] + lp[8];
        const float mval = s * inv9;
        float4 o;
        o.x = c4.x * mval;
        o.y = c4.y * mval;
        o.z = c4.z * mval;
        o.w = c4.w * mval;
        *(float4*)(out + pix * NF + (size_t)q * 4) = o;
    }
}

extern "C" void kernel_launch(void* const* d_in, const int* in_sizes, int n_in,
                              void* d_out, int out_size, void* d_ws, size_t ws_size,
                              hipStream_t stream) {
    const float* lfi    = (const float*)d_in[0];
    const float* f_maps = (const float*)d_in[1];
    float* out = (float*)d_out;

    // Workspace: hv [4*256*64] then comb [4*256*64]  (512 KiB total)
    float* hv   = (float*)d_ws;
    float* comb = hv + (size_t)BB * WW * NF;

    // 1) hv reduction: one block per (b,w)
    k_hv<<<BB * WW, 256, 0, stream>>>(f_maps, hv);
    // 2) per-b sum/max + comb coefficients
    k_comb<<<BB, 256, 0, stream>>>(hv, comb);
    // 3) main broadcast-multiply: one wave per (b,u,y) row -> 9216 waves
    k_main<<<(BB * UU * HH) / 4, 256, 0, stream>>>(lfi, comb, out);
}

// Round 3
// 145.728 us; speedup vs baseline: 2.1886x; 2.1886x over previous
//
#include <hip/hip_runtime.h>

// Shapes (fixed by the reference):
//   lfi:    [B=4, U=9, H=256, W=256, V=9]  f32
//   f_maps: [B=4, H=256, W=256, N=64]      f32
//   out:    [B=4, U=9, Y=256, X=256, N=64] f32
#define BB 4
#define UU 9
#define HH 256
#define WW 256
#define VV 9
#define NF 64
#define NPIX (BB * UU * HH * WW)   // 2,359,296 pixels (b,u,y,x)

typedef float f32x4 __attribute__((ext_vector_type(4)));   // native vector: OK for nontemporal builtins

// ---------------- Kernel 1: hv[b][w][n] = (1/H) * sum_h f_maps[b][h][w][n]
__global__ __launch_bounds__(256) void k_hv(const float* __restrict__ f,
                                            float* __restrict__ hv) {
    const int blk = blockIdx.x;            // b*W + w
    const int b = blk >> 8, w = blk & 255;
    const int t = threadIdx.x;
    const int n = t & 63, hc = t >> 6;     // 4 chunks of 64 h each

    float acc = 0.f;
    const float* p = f + (((size_t)(b * HH + hc * 64) * WW) + w) * NF + n;
    const size_t stride = (size_t)WW * NF; // one h step
    #pragma unroll 8
    for (int i = 0; i < 64; ++i) acc += p[(size_t)i * stride];

    __shared__ float red[4][64];
    red[hc][n] = acc;
    __syncthreads();
    if (t < 64) {
        float s = red[0][t] + red[1][t] + red[2][t] + red[3][t];
        hv[((size_t)b * WW + w) * NF + t] = s * (1.0f / HH);
    }
}

// ---------------- Kernel 2: per b:
//   s_mask[n]    = H * sum_w hv[b][w][n]
//   hvmax[n]     = max_w hv[b][w][n]
//   comb[b][y][n] = s_mask[n] * hv[b][y][n] / hvmax[n]
__global__ __launch_bounds__(256) void k_comb(const float* __restrict__ hv,
                                              float* __restrict__ comb) {
    const int b = blockIdx.x;
    const int t = threadIdx.x;
    const int n = t & 63, c = t >> 6;      // 4 chunks of 64 w each

    float s = 0.f, m = -1e30f;
    const float* p = hv + ((size_t)b * WW + c * 64) * NF + n;
    #pragma unroll 8
    for (int i = 0; i < 64; ++i) {
        float v = p[(size_t)i * NF];
        s += v;
        m = fmaxf(m, v);
    }

    __shared__ float rs[4][64], rm[4][64];
    __shared__ float fscale[64];
    rs[c][n] = s;
    rm[c][n] = m;
    __syncthreads();
    if (t < 64) {
        float ssum = (rs[0][t] + rs[1][t] + rs[2][t] + rs[3][t]) * (float)HH;
        float smax = fmaxf(fmaxf(rm[0][t], rm[1][t]), fmaxf(rm[2][t], rm[3][t]));
        fscale[t] = ssum / smax;
    }
    __syncthreads();

    const float sc = fscale[n];
    const float* p2 = hv + ((size_t)b * WW + c * 64) * NF + n;
    float* q = comb + ((size_t)b * WW + c * 64) * NF + n;
    #pragma unroll 8
    for (int i = 0; i < 64; ++i) q[(size_t)i * NF] = p2[(size_t)i * NF] * sc;
}

// ---------------- Kernel 3: mean over v.  mlfi[pix] = (1/9)*sum_v lfi[pix*9+v]
// One thread per pixel; 9 scalar loads (36 B, 4B-aligned) + 1 coalesced store.
__global__ __launch_bounds__(256) void k_mean(const float* __restrict__ lfi,
                                              float* __restrict__ mlfi) {
    const int pix = blockIdx.x * 256 + threadIdx.x;
    const float* lp = lfi + (size_t)pix * VV;
    float s = lp[0] + lp[1] + lp[2] + lp[3] + lp[4]
            + lp[5] + lp[6] + lp[7] + lp[8];
    mlfi[pix] = s * (1.0f / VV);
}

// ---------------- Kernel 4: one wave per (b,u,y) row.
// out[pix*64 + n] = mlfi[pix] * comb[(b*256+y)*64 + n]
// Per iteration: 1 broadcast dword load + 1 nontemporal 16B store.
__global__ __launch_bounds__(256) void k_out(const float* __restrict__ mlfi,
                                             const float* __restrict__ comb,
                                             float* __restrict__ out) {
    const int wid  = (int)((blockIdx.x * 256 + threadIdx.x) >> 6); // row id 0..9215
    const int lane = threadIdx.x & 63;
    const int y  = wid & 255;
    const int b  = (wid >> 8) / UU;

    const int q   = lane & 15;     // n-quad
    const int sub = lane >> 4;     // sub-pixel within group of 4

    const size_t rowpix = (size_t)wid * 256;   // pixel index at x=0
    const f32x4 c4 = *(const f32x4*)(comb + ((size_t)(b * 256 + y)) * NF + q * 4);

    #pragma unroll 8
    for (int g = 0; g < 64; ++g) {
        const size_t pix = rowpix + (size_t)g * 4 + sub;
        const float m = mlfi[pix];
        f32x4 o = c4 * m;
        __builtin_nontemporal_store(o, (f32x4*)(out + pix * NF + (size_t)q * 4));
    }
}

extern "C" void kernel_launch(void* const* d_in, const int* in_sizes, int n_in,
                              void* d_out, int out_size, void* d_ws, size_t ws_size,
                              hipStream_t stream) {
    const float* lfi    = (const float*)d_in[0];
    const float* f_maps = (const float*)d_in[1];
    float* out = (float*)d_out;

    // Workspace layout (floats): hv [B*W*N], comb [B*W*N], mlfi [NPIX]  (~10 MB)
    float* hv   = (float*)d_ws;
    float* comb = hv + (size_t)BB * WW * NF;
    float* mlfi = comb + (size_t)BB * WW * NF;

    // 1) hv reduction: one block per (b,w)
    k_hv<<<BB * WW, 256, 0, stream>>>(f_maps, hv);
    // 2) per-b sum/max + comb coefficients
    k_comb<<<BB, 256, 0, stream>>>(hv, comb);
    // 3) v-mean of lfi: one thread per pixel
    k_mean<<<NPIX / 256, 256, 0, stream>>>(lfi, mlfi);
    // 4) broadcast-multiply write: one wave per (b,u,y) row -> 9216 waves
    k_out<<<(BB * UU * HH) / 4, 256, 0, stream>>>(mlfi, comb, out);
}

// Round 4
// 127.964 us; speedup vs baseline: 2.4924x; 1.1388x over previous
//
#include <hip/hip_runtime.h>

// Shapes (fixed by the reference):
//   lfi:    [B=4, U=9, H=256, W=256, V=9]  f32
//   f_maps: [B=4, H=256, W=256, N=64]      f32
//   out:    [B=4, U=9, Y=256, X=256, N=64] f32
#define BB 4
#define UU 9
#define HH 256
#define WW 256
#define VV 9
#define NF 64
#define NROWS (BB * UU * HH)       // 9216 (b,u,y) rows
#define ROWS 4                     // rows per block in k_out

typedef float f32x4 __attribute__((ext_vector_type(4)));

// ---------------- Kernel 1: hv[b][w][n] = (1/H) * sum_h f_maps[b][h][w][n]
__global__ __launch_bounds__(256) void k_hv(const float* __restrict__ f,
                                            float* __restrict__ hv) {
    const int blk = blockIdx.x;            // b*W + w
    const int b = blk >> 8, w = blk & 255;
    const int t = threadIdx.x;
    const int n = t & 63, hc = t >> 6;     // 4 chunks of 64 h each

    float acc = 0.f;
    const float* p = f + (((size_t)(b * HH + hc * 64) * WW) + w) * NF + n;
    const size_t stride = (size_t)WW * NF; // one h step
    #pragma unroll 8
    for (int i = 0; i < 64; ++i) acc += p[(size_t)i * stride];

    __shared__ float red[4][64];
    red[hc][n] = acc;
    __syncthreads();
    if (t < 64) {
        float s = red[0][t] + red[1][t] + red[2][t] + red[3][t];
        hv[((size_t)b * WW + w) * NF + t] = s * (1.0f / HH);
    }
}

// ---------------- Kernel 2: per b:
//   s_mask[n]    = H * sum_w hv[b][w][n]
//   hvmax[n]     = max_w hv[b][w][n]
//   comb[b][y][n] = s_mask[n] * hv[b][y][n] / hvmax[n]
__global__ __launch_bounds__(256) void k_comb(const float* __restrict__ hv,
                                              float* __restrict__ comb) {
    const int b = blockIdx.x;
    const int t = threadIdx.x;
    const int n = t & 63, c = t >> 6;      // 4 chunks of 64 w each

    float s = 0.f, m = -1e30f;
    const float* p = hv + ((size_t)b * WW + c * 64) * NF + n;
    #pragma unroll 8
    for (int i = 0; i < 64; ++i) {
        float v = p[(size_t)i * NF];
        s += v;
        m = fmaxf(m, v);
    }

    __shared__ float rs[4][64], rm[4][64];
    __shared__ float fscale[64];
    rs[c][n] = s;
    rm[c][n] = m;
    __syncthreads();
    if (t < 64) {
        float ssum = (rs[0][t] + rs[1][t] + rs[2][t] + rs[3][t]) * (float)HH;
        float smax = fmaxf(fmaxf(rm[0][t], rm[1][t]), fmaxf(rm[2][t], rm[3][t]));
        fscale[t] = ssum / smax;
    }
    __syncthreads();

    const float sc = fscale[n];
    const float* p2 = hv + ((size_t)b * WW + c * 64) * NF + n;
    float* q = comb + ((size_t)b * WW + c * 64) * NF + n;
    #pragma unroll 8
    for (int i = 0; i < 64; ++i) q[(size_t)i * NF] = p2[(size_t)i * NF] * sc;
}

// ---------------- Kernel 3 (fused mean + broadcast-multiply write).
// Block owns ROWS=4 consecutive (b,u,y) rows:
//   stage 36 KB of lfi (coalesced float4) -> LDS
//   per-thread v-means (conflict-free: 9 coprime 32) -> smean[1024]
//   wave w writes row w: 1 LDS broadcast + 1 nontemporal 16B store per iter
__global__ __launch_bounds__(256) void k_out(const float* __restrict__ lfi,
                                             const float* __restrict__ comb,
                                             float* __restrict__ out) {
    __shared__ float slfi[ROWS * WW * VV];   // 4*256*9 = 9216 floats, 36 KB
    __shared__ float smean[ROWS * WW];       // 1024 floats, 4 KB

    const int blk = blockIdx.x;              // row group
    const int t = threadIdx.x;

    // --- stage: 4 rows of lfi = 2304 float4s, 9 per thread, fully coalesced
    const f32x4* src = (const f32x4*)(lfi + (size_t)blk * (ROWS * WW * VV));
    f32x4* dst = (f32x4*)slfi;
    #pragma unroll
    for (int j = 0; j < 9; ++j) dst[t + 256 * j] = src[t + 256 * j];
    __syncthreads();

    // --- v-means: thread t -> local pixels t, t+256, t+512, t+768
    #pragma unroll
    for (int j = 0; j < ROWS; ++j) {
        const int p = t + 256 * j;
        const float* lp = slfi + p * VV;
        float s = lp[0] + lp[1] + lp[2] + lp[3] + lp[4]
                + lp[5] + lp[6] + lp[7] + lp[8];
        smean[p] = s * (1.0f / VV);
    }
    __syncthreads();

    // --- write: wave w owns local row w (global row = blk*ROWS + w)
    const int lane = t & 63, w = t >> 6;
    const int rowid = blk * ROWS + w;
    const int y = rowid & 255;
    const int b = (rowid >> 8) / UU;

    const int q   = lane & 15;   // n-quad
    const int sub = lane >> 4;   // sub-pixel within group of 4

    const f32x4 c4 = *(const f32x4*)(comb + ((size_t)(b * WW + y)) * NF + q * 4);
    float* obase = out + (size_t)rowid * WW * NF + (size_t)q * 4;
    const float* mbase = smean + w * WW;

    #pragma unroll 8
    for (int g = 0; g < 64; ++g) {
        const int pl = g * 4 + sub;          // local pixel in row
        const float m = mbase[pl];           // LDS broadcast (16 lanes share)
        f32x4 o = c4 * m;
        __builtin_nontemporal_store(o, (f32x4*)(obase + (size_t)pl * NF));
    }
}

extern "C" void kernel_launch(void* const* d_in, const int* in_sizes, int n_in,
                              void* d_out, int out_size, void* d_ws, size_t ws_size,
                              hipStream_t stream) {
    const float* lfi    = (const float*)d_in[0];
    const float* f_maps = (const float*)d_in[1];
    float* out = (float*)d_out;

    // Workspace layout (floats): hv [B*W*N], comb [B*W*N]   (512 KiB)
    float* hv   = (float*)d_ws;
    float* comb = hv + (size_t)BB * WW * NF;

    // 1) hv reduction: one block per (b,w)
    k_hv<<<BB * WW, 256, 0, stream>>>(f_maps, hv);
    // 2) per-b sum/max + comb coefficients
    k_comb<<<BB, 256, 0, stream>>>(hv, comb);
    // 3) fused v-mean + broadcast-multiply write: 4 rows per block
    k_out<<<NROWS / ROWS, 256, 0, stream>>>(lfi, comb, out);
}

// Round 5
// 119.579 us; speedup vs baseline: 2.6672x; 1.0701x over previous
//
#include <hip/hip_runtime.h>

// Shapes (fixed by the reference):
//   lfi:    [B=4, U=9, H=256, W=256, V=9]  f32
//   f_maps: [B=4, H=256, W=256, N=64]      f32
//   out:    [B=4, U=9, Y=256, X=256, N=64] f32
#define BB 4
#define UU 9
#define HH 256
#define WW 256
#define VV 9
#define NF 64
#define NROWS (BB * UU * HH)       // 9216 (b,u,y) rows
#define ROWS 2                     // rows per block in k_out (20.5 KB LDS -> 8 blocks/CU)

typedef float f32x4 __attribute__((ext_vector_type(4)));
typedef float f32x2 __attribute__((ext_vector_type(2)));

// ---------------- Kernel 1: hv[b][w][n] = (1/H) * sum_h f_maps[b][h][w][n]
__global__ __launch_bounds__(256) void k_hv(const float* __restrict__ f,
                                            float* __restrict__ hv) {
    const int blk = blockIdx.x;            // b*W + w
    const int b = blk >> 8, w = blk & 255;
    const int t = threadIdx.x;
    const int n = t & 63, hc = t >> 6;     // 4 chunks of 64 h each

    float acc = 0.f;
    const float* p = f + (((size_t)(b * HH + hc * 64) * WW) + w) * NF + n;
    const size_t stride = (size_t)WW * NF; // one h step
    #pragma unroll 8
    for (int i = 0; i < 64; ++i) acc += p[(size_t)i * stride];

    __shared__ float red[4][64];
    red[hc][n] = acc;
    __syncthreads();
    if (t < 64) {
        float s = red[0][t] + red[1][t] + red[2][t] + red[3][t];
        hv[((size_t)b * WW + w) * NF + t] = s * (1.0f / HH);
    }
}

// ---------------- Kernel 2: fscale[b][n] = (H * sum_w hv[b][w][n]) / max_w hv[b][w][n]
__global__ __launch_bounds__(256) void k_fscale(const float* __restrict__ hv,
                                                float* __restrict__ fscale) {
    const int b = blockIdx.x;
    const int t = threadIdx.x;
    const int n = t & 63, c = t >> 6;      // 4 chunks of 64 w each

    float s = 0.f, m = -1e30f;
    const float* p = hv + ((size_t)b * WW + c * 64) * NF + n;
    #pragma unroll 8
    for (int i = 0; i < 64; ++i) {
        float v = p[(size_t)i * NF];
        s += v;
        m = fmaxf(m, v);
    }

    __shared__ float rs[4][64], rm[4][64];
    rs[c][n] = s;
    rm[c][n] = m;
    __syncthreads();
    if (t < 64) {
        float ssum = (rs[0][t] + rs[1][t] + rs[2][t] + rs[3][t]) * (float)HH;
        float smax = fmaxf(fmaxf(rm[0][t], rm[1][t]), fmaxf(rm[2][t], rm[3][t]));
        fscale[b * NF + t] = ssum / smax;
    }
}

// ---------------- Kernel 3 (fused mean + broadcast-multiply write).
// Block owns ROWS=2 consecutive (b,u,y) rows:
//   stage 18 KB of lfi (coalesced float2 x9/thread) -> LDS
//   per-thread v-means (9 coprime 32 -> conflict-free) -> smean[512]
//   2 waves per row; per iter: 1 LDS broadcast + 1 nontemporal 16B store
__global__ __launch_bounds__(256) void k_out(const float* __restrict__ lfi,
                                             const float* __restrict__ hv,
                                             const float* __restrict__ fscale,
                                             float* __restrict__ out) {
    __shared__ float slfi[ROWS * WW * VV];   // 2*256*9 = 4608 floats, 18 KB
    __shared__ float smean[ROWS * WW];       // 512 floats, 2 KB

    const int blk = blockIdx.x;              // row pair
    const int t = threadIdx.x;

    // --- stage: 2 rows of lfi = 2304 float2s, 9 per thread, fully coalesced
    const f32x2* src = (const f32x2*)(lfi + (size_t)blk * (ROWS * WW * VV));
    f32x2* dst = (f32x2*)slfi;
    #pragma unroll
    for (int j = 0; j < 9; ++j) dst[t + 256 * j] = src[t + 256 * j];
    __syncthreads();

    // --- v-means: thread t -> local pixels t, t+256
    #pragma unroll
    for (int j = 0; j < ROWS; ++j) {
        const int p = t + 256 * j;
        const float* lp = slfi + p * VV;
        float s = lp[0] + lp[1] + lp[2] + lp[3] + lp[4]
                + lp[5] + lp[6] + lp[7] + lp[8];
        smean[p] = s * (1.0f / VV);
    }
    __syncthreads();

    // --- write: wave w -> row r = w>>1, x-half = (w&1)*128
    const int lane = t & 63, w = t >> 6;
    const int r = w >> 1, xh = (w & 1) * 128;
    const int rowid = blk * ROWS + r;
    const int y = rowid & 255;
    const int b = (rowid >> 8) / UU;

    const int q   = lane & 15;   // n-quad
    const int sub = lane >> 4;   // sub-pixel within group of 4

    const f32x4 f4 = *(const f32x4*)(fscale + (size_t)b * NF + q * 4);
    const f32x4 h4 = *(const f32x4*)(hv + ((size_t)(b * WW + y)) * NF + q * 4);
    const f32x4 c4 = f4 * h4;

    float* obase = out + (size_t)rowid * WW * NF + (size_t)q * 4;
    const float* mbase = smean + r * WW;

    #pragma unroll 8
    for (int g = 0; g < 32; ++g) {
        const int x = xh + g * 4 + sub;      // pixel in row
        const float m = mbase[x];            // LDS broadcast (16 lanes share)
        f32x4 o = c4 * m;
        __builtin_nontemporal_store(o, (f32x4*)(obase + (size_t)x * NF));
    }
}

extern "C" void kernel_launch(void* const* d_in, const int* in_sizes, int n_in,
                              void* d_out, int out_size, void* d_ws, size_t ws_size,
                              hipStream_t stream) {
    const float* lfi    = (const float*)d_in[0];
    const float* f_maps = (const float*)d_in[1];
    float* out = (float*)d_out;

    // Workspace layout (floats): hv [B*W*N], fscale [B*N]   (~257 KiB)
    float* hv     = (float*)d_ws;
    float* fscale = hv + (size_t)BB * WW * NF;

    // 1) hv reduction: one block per (b,w)
    k_hv<<<BB * WW, 256, 0, stream>>>(f_maps, hv);
    // 2) per-b scale factors (s_mask / hvmax)
    k_fscale<<<BB, 256, 0, stream>>>(hv, fscale);
    // 3) fused v-mean + broadcast-multiply write: 2 rows per block
    k_out<<<NROWS / ROWS, 256, 0, stream>>>(lfi, hv, fscale, out);
}